// Round 1
// baseline (691.562 us; speedup 1.0000x reference)
//
#include <hip/hip_runtime.h>

#define N_NODES 100000
#define N_EDGES 1600000
#define DIN 64
#define DOUT 32
#define NEG_SLOPE 0.01f

// ---------------- degree / norm ----------------
__global__ void deg_init_kernel(float* __restrict__ deg) {
    int i = blockIdx.x * blockDim.x + threadIdx.x;
    if (i < N_NODES) deg[i] = 1.0f;  // self-loop
}

__global__ void deg_scatter_kernel(const int* __restrict__ dst, float* __restrict__ deg) {
    int e = blockIdx.x * blockDim.x + threadIdx.x;
    if (e < N_EDGES) atomicAdd(&deg[dst[e]], 1.0f);
}

__global__ void deg_rsqrt_kernel(float* __restrict__ deg) {
    int i = blockIdx.x * blockDim.x + threadIdx.x;
    if (i < N_NODES) deg[i] = rsqrtf(deg[i]);
}

// ---------------- GEMM: H = X @ W  (K = 64) ----------------
// 4 rows per block of 256 threads; thread computes one (row, col) with col in [0,64)
__global__ void gemm_k64_n64_kernel(const float* __restrict__ X, const float* __restrict__ W,
                                    float* __restrict__ H) {
    __shared__ float Ws[64 * 64];
    __shared__ float Xs[4][64];
    int tid = threadIdx.x;
    // load W (4096 floats) with float4: 256 threads x 4 float4
    {
        const float4* Wv = (const float4*)W;
        float4* Wsv = (float4*)Ws;
#pragma unroll
        for (int i = 0; i < 4; ++i) Wsv[tid + 256 * i] = Wv[tid + 256 * i];
    }
    int row0 = blockIdx.x * 4;
    int r = tid >> 6;       // 0..3
    int col = tid & 63;     // 0..63
    Xs[r][col] = X[(row0 + r) * 64 + col];
    __syncthreads();

    float sum = 0.f;
#pragma unroll
    for (int k = 0; k < 64; ++k) sum += Xs[r][k] * Ws[k * 64 + col];
    H[(row0 + r) * 64 + col] = sum;
}

// 8 rows per block of 256 threads; col in [0,32)
__global__ void gemm_k64_n32_kernel(const float* __restrict__ X, const float* __restrict__ W,
                                    float* __restrict__ H) {
    __shared__ float Ws[64 * 32];
    __shared__ float Xs[8][64];
    int tid = threadIdx.x;
    {
        const float4* Wv = (const float4*)W;
        float4* Wsv = (float4*)Ws;
#pragma unroll
        for (int i = 0; i < 2; ++i) Wsv[tid + 256 * i] = Wv[tid + 256 * i];
    }
    int row0 = blockIdx.x * 8;
    // load 8 rows x 64 = 512 floats
    {
        int idx = tid;
#pragma unroll
        for (int i = 0; i < 2; ++i, idx += 256) Xs[idx >> 6][idx & 63] = X[row0 * 64 + idx];
    }
    __syncthreads();

    int r = tid >> 5;       // 0..7
    int col = tid & 31;     // 0..31
    float sum = 0.f;
#pragma unroll
    for (int k = 0; k < 64; ++k) sum += Xs[r][k] * Ws[k * 32 + col];
    H[(row0 + r) * 32 + col] = sum;
}

// ---------------- aggregation ----------------
// init: self-loop contribution (+ optional bias)
template <int D, bool ADD_BIAS>
__global__ void agg_init_kernel(const float* __restrict__ H, const float* __restrict__ dinv,
                                const float* __restrict__ bias, float* __restrict__ out) {
    int idx = blockIdx.x * blockDim.x + threadIdx.x;
    if (idx < N_NODES * D) {
        int row = idx / D;
        int d = idx % D;
        float di = dinv[row];
        float v = H[idx] * di * di;
        if (ADD_BIAS) v += bias[d];
        out[idx] = v;
    }
}

// edge scatter: out[dst] += H[src] * dinv[src]*dinv[dst]
template <int D>
__global__ void agg_scatter_kernel(const int* __restrict__ src, const int* __restrict__ dst,
                                   const float* __restrict__ dinv, const float* __restrict__ H,
                                   float* __restrict__ out) {
    long long t = (long long)blockIdx.x * blockDim.x + threadIdx.x;
    int e = (int)(t / D);
    int d = (int)(t % D);
    if (e < N_EDGES) {
        int s = src[e];
        int dd = dst[e];
        float norm = dinv[s] * dinv[dd];
        atomicAdd(&out[(long long)dd * D + d], H[(long long)s * D + d] * norm);
    }
}

// bias + leaky relu, in-place capable (reads A, writes B)
__global__ void bias_leaky_kernel(const float* __restrict__ A, const float* __restrict__ b,
                                  float* __restrict__ B) {
    int idx = blockIdx.x * blockDim.x + threadIdx.x;
    if (idx < N_NODES * DIN) {
        float v = A[idx] + b[idx & 63];
        B[idx] = v > 0.f ? v : NEG_SLOPE * v;
    }
}

extern "C" void kernel_launch(void* const* d_in, const int* in_sizes, int n_in,
                              void* d_out, int out_size, void* d_ws, size_t ws_size,
                              hipStream_t stream) {
    const float* x = (const float*)d_in[0];
    const int* ei = (const int*)d_in[1];       // [2, E] row-major: src row then dst row
    const float* W1 = (const float*)d_in[2];
    const float* b1 = (const float*)d_in[3];
    const float* W2 = (const float*)d_in[4];
    const float* b2 = (const float*)d_in[5];
    float* out = (float*)d_out;

    const int* src = ei;
    const int* dst = ei + N_EDGES;

    float* dinv = (float*)d_ws;                 // N floats
    float* h1 = dinv + N_NODES;                 // N*64
    float* agg1 = h1 + (size_t)N_NODES * DIN;   // N*64
    float* h2 = agg1 + (size_t)N_NODES * DIN;   // N*32

    // 1. degrees -> dinv
    deg_init_kernel<<<(N_NODES + 255) / 256, 256, 0, stream>>>(dinv);
    deg_scatter_kernel<<<(N_EDGES + 255) / 256, 256, 0, stream>>>(dst, dinv);
    deg_rsqrt_kernel<<<(N_NODES + 255) / 256, 256, 0, stream>>>(dinv);

    // 2. h1 = x @ W1
    gemm_k64_n64_kernel<<<N_NODES / 4, 256, 0, stream>>>(x, W1, h1);

    // 3. aggregate layer 1 (no bias in init; bias added in post pass with leaky)
    agg_init_kernel<DIN, false><<<(N_NODES * DIN + 255) / 256, 256, 0, stream>>>(h1, dinv, nullptr, agg1);
    agg_scatter_kernel<DIN><<<(int)(((long long)N_EDGES * DIN + 255) / 256), 256, 0, stream>>>(
        src, dst, dinv, h1, agg1);
    bias_leaky_kernel<<<(N_NODES * DIN + 255) / 256, 256, 0, stream>>>(agg1, b1, h1);

    // 4. h2 = h @ W2
    gemm_k64_n32_kernel<<<N_NODES / 8, 256, 0, stream>>>(h1, W2, h2);

    // 5. aggregate layer 2, bias fused into init, write directly to d_out
    agg_init_kernel<DOUT, true><<<(N_NODES * DOUT + 255) / 256, 256, 0, stream>>>(h2, dinv, b2, out);
    agg_scatter_kernel<DOUT><<<(int)(((long long)N_EDGES * DOUT + 255) / 256), 256, 0, stream>>>(
        src, dst, dinv, h2, out);
}

// Round 2
// 594.727 us; speedup vs baseline: 1.1628x; 1.1628x over previous
//
#include <hip/hip_runtime.h>

#define N_NODES 100000
#define N_EDGES 1600000
#define DIN 64
#define DOUT 32
#define NEG_SLOPE 0.01f

// ---------------- CSR build ----------------
__global__ void zero_cnt_kernel(int* __restrict__ cnt) {
    int i = blockIdx.x * blockDim.x + threadIdx.x;
    if (i < N_NODES) cnt[i] = 0;
}

__global__ void count_kernel(const int* __restrict__ dst, int* __restrict__ cnt) {
    int e = blockIdx.x * blockDim.x + threadIdx.x;
    if (e < N_EDGES) atomicAdd(&cnt[dst[e]], 1);
}

// single-block exclusive scan of cnt[0..N) -> rowptr[0..N]
__global__ __launch_bounds__(1024) void scan_kernel(const int* __restrict__ cnt,
                                                    int* __restrict__ rowptr) {
    __shared__ int partial[1024];
    const int chunk = (N_NODES + 1023) / 1024;  // 98
    int t = threadIdx.x;
    int beg = t * chunk;
    int end = min(beg + chunk, N_NODES);
    int s = 0;
    for (int i = beg; i < end; ++i) s += cnt[i];
    partial[t] = s;
    __syncthreads();
    // Hillis-Steele inclusive scan
    for (int off = 1; off < 1024; off <<= 1) {
        int v = partial[t];
        int add = (t >= off) ? partial[t - off] : 0;
        __syncthreads();
        partial[t] = v + add;
        __syncthreads();
    }
    int run = (t == 0) ? 0 : partial[t - 1];
    for (int i = beg; i < end; ++i) {
        rowptr[i] = run;
        run += cnt[i];
    }
    if (t == 1023) rowptr[N_NODES] = run;  // == E
}

// dinv = rsqrt(indeg+1); pos = rowptr copy for the fill pass
__global__ void dinv_pos_kernel(const int* __restrict__ cnt, const int* __restrict__ rowptr,
                                float* __restrict__ dinv, int* __restrict__ pos) {
    int i = blockIdx.x * blockDim.x + threadIdx.x;
    if (i < N_NODES) {
        dinv[i] = rsqrtf((float)(cnt[i] + 1));
        pos[i] = rowptr[i];
    }
}

__global__ void fill_kernel(const int* __restrict__ src, const int* __restrict__ dst,
                            int* __restrict__ pos, int* __restrict__ colsrc) {
    int e = blockIdx.x * blockDim.x + threadIdx.x;
    if (e < N_EDGES) {
        int idx = atomicAdd(&pos[dst[e]], 1);
        colsrc[idx] = src[e];
    }
}

// ---------------- GEMM: H = X @ W  (K = 64) ----------------
__global__ void gemm_k64_n64_kernel(const float* __restrict__ X, const float* __restrict__ W,
                                    float* __restrict__ H) {
    __shared__ float Ws[64 * 64];
    __shared__ float Xs[4][64];
    int tid = threadIdx.x;
    {
        const float4* Wv = (const float4*)W;
        float4* Wsv = (float4*)Ws;
#pragma unroll
        for (int i = 0; i < 4; ++i) Wsv[tid + 256 * i] = Wv[tid + 256 * i];
    }
    int row0 = blockIdx.x * 4;
    int r = tid >> 6;
    int col = tid & 63;
    Xs[r][col] = X[(row0 + r) * 64 + col];
    __syncthreads();

    float sum = 0.f;
#pragma unroll
    for (int k = 0; k < 64; ++k) sum += Xs[r][k] * Ws[k * 64 + col];
    H[(row0 + r) * 64 + col] = sum;
}

__global__ void gemm_k64_n32_kernel(const float* __restrict__ X, const float* __restrict__ W,
                                    float* __restrict__ H) {
    __shared__ float Ws[64 * 32];
    __shared__ float Xs[8][64];
    int tid = threadIdx.x;
    {
        const float4* Wv = (const float4*)W;
        float4* Wsv = (float4*)Ws;
#pragma unroll
        for (int i = 0; i < 2; ++i) Wsv[tid + 256 * i] = Wv[tid + 256 * i];
    }
    int row0 = blockIdx.x * 8;
    {
        int idx = tid;
#pragma unroll
        for (int i = 0; i < 2; ++i, idx += 256) Xs[idx >> 6][idx & 63] = X[row0 * 64 + idx];
    }
    __syncthreads();

    int r = tid >> 5;
    int col = tid & 31;
    float sum = 0.f;
#pragma unroll
    for (int k = 0; k < 64; ++k) sum += Xs[r][k] * Ws[k * 32 + col];
    H[(row0 + r) * 32 + col] = sum;
}

// ---------------- gather aggregation ----------------
// one wave (64 lanes) per node, lane = feature dim; bias + leaky fused
__global__ void gather64_kernel(const float* __restrict__ H, const int* __restrict__ rowptr,
                                const int* __restrict__ colsrc, const float* __restrict__ dinv,
                                const float* __restrict__ bias, float* __restrict__ out) {
    int wid = (blockIdx.x * blockDim.x + threadIdx.x) >> 6;
    int lane = threadIdx.x & 63;
    if (wid >= N_NODES) return;
    int v = wid;
    float dv = dinv[v];
    int beg = rowptr[v], end = rowptr[v + 1];
    float acc = H[(size_t)v * 64 + lane] * dv * dv;  // self-loop
    for (int j0 = beg; j0 < end; j0 += 64) {
        int myj = j0 + lane;
        int s = 0;
        float w = 0.f;
        if (myj < end) {
            s = colsrc[myj];
            w = dinv[s] * dv;
        }
        int cnt = min(64, end - j0);
        for (int t = 0; t < cnt; ++t) {
            int sv = __shfl(s, t);
            float wv = __shfl(w, t);
            acc += H[(size_t)sv * 64 + lane] * wv;
        }
    }
    acc += bias[lane];
    acc = acc > 0.f ? acc : NEG_SLOPE * acc;
    out[(size_t)v * 64 + lane] = acc;
}

// half-wave (32 lanes) per node for D=32; bias fused, writes final output
__global__ void gather32_kernel(const float* __restrict__ H, const int* __restrict__ rowptr,
                                const int* __restrict__ colsrc, const float* __restrict__ dinv,
                                const float* __restrict__ bias, float* __restrict__ out) {
    int gw = (blockIdx.x * blockDim.x + threadIdx.x) >> 5;
    int lane = threadIdx.x & 31;
    if (gw >= N_NODES) return;
    int v = gw;
    float dv = dinv[v];
    int beg = rowptr[v], end = rowptr[v + 1];
    float acc = H[(size_t)v * 32 + lane] * dv * dv;  // self-loop
    for (int j0 = beg; j0 < end; j0 += 32) {
        int myj = j0 + lane;
        int s = 0;
        float w = 0.f;
        if (myj < end) {
            s = colsrc[myj];
            w = dinv[s] * dv;
        }
        int cnt = min(32, end - j0);
        for (int t = 0; t < cnt; ++t) {
            int sv = __shfl(s, t, 32);
            float wv = __shfl(w, t, 32);
            acc += H[(size_t)sv * 32 + lane] * wv;
        }
    }
    acc += bias[lane];
    out[(size_t)v * 32 + lane] = acc;
}

extern "C" void kernel_launch(void* const* d_in, const int* in_sizes, int n_in,
                              void* d_out, int out_size, void* d_ws, size_t ws_size,
                              hipStream_t stream) {
    const float* x = (const float*)d_in[0];
    const int* ei = (const int*)d_in[1];  // [2,E]: src row then dst row
    const float* W1 = (const float*)d_in[2];
    const float* b1 = (const float*)d_in[3];
    const float* W2 = (const float*)d_in[4];
    const float* b2 = (const float*)d_in[5];
    float* out = (float*)d_out;

    const int* src = ei;
    const int* dst = ei + N_EDGES;

    // workspace layout (~59 MB)
    float* dinv = (float*)d_ws;               // N
    int* rowptr = (int*)(dinv + N_NODES);     // N+1
    int* cnt = rowptr + N_NODES + 1;          // N
    int* pos = cnt + N_NODES;                 // N
    int* colsrc = pos + N_NODES;              // E
    float* h1 = (float*)(colsrc + N_EDGES);   // N*64
    float* h1p = h1 + (size_t)N_NODES * DIN;  // N*64
    float* h2 = h1;                           // alias: h1 dead after gather64

    // CSR build + norms
    zero_cnt_kernel<<<(N_NODES + 255) / 256, 256, 0, stream>>>(cnt);
    count_kernel<<<(N_EDGES + 255) / 256, 256, 0, stream>>>(dst, cnt);
    scan_kernel<<<1, 1024, 0, stream>>>(cnt, rowptr);
    dinv_pos_kernel<<<(N_NODES + 255) / 256, 256, 0, stream>>>(cnt, rowptr, dinv, pos);
    fill_kernel<<<(N_EDGES + 255) / 256, 256, 0, stream>>>(src, dst, pos, colsrc);

    // layer 1
    gemm_k64_n64_kernel<<<N_NODES / 4, 256, 0, stream>>>(x, W1, h1);
    gather64_kernel<<<(N_NODES * 64 + 255) / 256, 256, 0, stream>>>(h1, rowptr, colsrc, dinv, b1, h1p);

    // layer 2
    gemm_k64_n32_kernel<<<N_NODES / 8, 256, 0, stream>>>(h1p, W2, h2);
    gather32_kernel<<<(N_NODES * 32 + 255) / 256, 256, 0, stream>>>(h2, rowptr, colsrc, dinv, b2, out);
}

// Round 3
// 438.895 us; speedup vs baseline: 1.5757x; 1.3551x over previous
//
#include <hip/hip_runtime.h>

#define N_NODES 100000
#define N_EDGES 1600000
#define DIN 64
#define DOUT 32
#define NEG_SLOPE 0.01f
#define NBLK ((N_NODES + 255) / 256)  // 391

// ---------------- CSR build ----------------
__global__ void zero_cnt_kernel(int* __restrict__ cnt) {
    int i = blockIdx.x * blockDim.x + threadIdx.x;
    if (i < N_NODES) cnt[i] = 0;
}

__global__ void count_kernel(const int* __restrict__ dst, int* __restrict__ cnt) {
    int e = blockIdx.x * blockDim.x + threadIdx.x;
    if (e < N_EDGES) atomicAdd(&cnt[dst[e]], 1);
}

// phase A: per-block sums of cnt
__global__ void blocksum_kernel(const int* __restrict__ cnt, int* __restrict__ bsum) {
    int i = blockIdx.x * 256 + threadIdx.x;
    int v = (i < N_NODES) ? cnt[i] : 0;
#pragma unroll
    for (int off = 32; off; off >>= 1) v += __shfl_down(v, off);
    __shared__ int ws[4];
    if ((threadIdx.x & 63) == 0) ws[threadIdx.x >> 6] = v;
    __syncthreads();
    if (threadIdx.x == 0) bsum[blockIdx.x] = ws[0] + ws[1] + ws[2] + ws[3];
}

// phase B: exclusive scan of the 391 block sums (one small block)
__global__ __launch_bounds__(512) void scan_bsum_kernel(const int* __restrict__ bsum,
                                                        int* __restrict__ bofs) {
    __shared__ int sh[512];
    int t = threadIdx.x;
    int v = (t < NBLK) ? bsum[t] : 0;
    sh[t] = v;
    __syncthreads();
    for (int off = 1; off < 512; off <<= 1) {
        int a = sh[t];
        int add = (t >= off) ? sh[t - off] : 0;
        __syncthreads();
        sh[t] = a + add;
        __syncthreads();
    }
    if (t < NBLK) bofs[t] = sh[t] - v;  // exclusive
}

// phase C: in-block exclusive scan + block offset -> rowptr; also dinv, pos
__global__ void rowptr_kernel(const int* __restrict__ cnt, const int* __restrict__ bofs,
                              int* __restrict__ rowptr, int* __restrict__ pos,
                              float* __restrict__ dinv) {
    int i = blockIdx.x * 256 + threadIdx.x;
    int v = (i < N_NODES) ? cnt[i] : 0;
    int lane = threadIdx.x & 63;
    int w = threadIdx.x >> 6;
    int x = v;
#pragma unroll
    for (int off = 1; off < 64; off <<= 1) {
        int n = __shfl_up(x, off);
        if (lane >= off) x += n;
    }
    __shared__ int wtot[4];
    if (lane == 63) wtot[w] = x;
    __syncthreads();
    int wofs = 0;
    for (int k = 0; k < w; ++k) wofs += wtot[k];
    int excl = x - v + wofs + bofs[blockIdx.x];
    if (i < N_NODES) {
        rowptr[i] = excl;
        pos[i] = excl;
        dinv[i] = rsqrtf((float)(v + 1));
        if (i == N_NODES - 1) rowptr[N_NODES] = excl + v;
    }
}

__global__ void fill_kernel(const int* __restrict__ src, const int* __restrict__ dst,
                            int* __restrict__ pos, int* __restrict__ colsrc) {
    int e = blockIdx.x * blockDim.x + threadIdx.x;
    if (e < N_EDGES) {
        int idx = atomicAdd(&pos[dst[e]], 1);
        colsrc[idx] = src[e];
    }
}

// ---------------- GEMM: H = X @ W  (K = 64) ----------------
__global__ void gemm_k64_n64_kernel(const float* __restrict__ X, const float* __restrict__ W,
                                    float* __restrict__ H) {
    __shared__ float Ws[64 * 64];
    __shared__ float Xs[4][64];
    int tid = threadIdx.x;
    {
        const float4* Wv = (const float4*)W;
        float4* Wsv = (float4*)Ws;
#pragma unroll
        for (int i = 0; i < 4; ++i) Wsv[tid + 256 * i] = Wv[tid + 256 * i];
    }
    int row0 = blockIdx.x * 4;
    int r = tid >> 6;
    int col = tid & 63;
    Xs[r][col] = X[(row0 + r) * 64 + col];
    __syncthreads();

    float sum = 0.f;
#pragma unroll
    for (int k = 0; k < 64; ++k) sum += Xs[r][k] * Ws[k * 64 + col];
    H[(row0 + r) * 64 + col] = sum;
}

__global__ void gemm_k64_n32_kernel(const float* __restrict__ X, const float* __restrict__ W,
                                    float* __restrict__ H) {
    __shared__ float Ws[64 * 32];
    __shared__ float Xs[8][64];
    int tid = threadIdx.x;
    {
        const float4* Wv = (const float4*)W;
        float4* Wsv = (float4*)Ws;
#pragma unroll
        for (int i = 0; i < 2; ++i) Wsv[tid + 256 * i] = Wv[tid + 256 * i];
    }
    int row0 = blockIdx.x * 8;
    {
        int idx = tid;
#pragma unroll
        for (int i = 0; i < 2; ++i, idx += 256) Xs[idx >> 6][idx & 63] = X[row0 * 64 + idx];
    }
    __syncthreads();

    int r = tid >> 5;
    int col = tid & 31;
    float sum = 0.f;
#pragma unroll
    for (int k = 0; k < 64; ++k) sum += Xs[r][k] * Ws[k * 32 + col];
    H[(row0 + r) * 32 + col] = sum;
}

// ---------------- gather aggregation ----------------
__global__ void gather64_kernel(const float* __restrict__ H, const int* __restrict__ rowptr,
                                const int* __restrict__ colsrc, const float* __restrict__ dinv,
                                const float* __restrict__ bias, float* __restrict__ out) {
    int wid = (blockIdx.x * blockDim.x + threadIdx.x) >> 6;
    int lane = threadIdx.x & 63;
    if (wid >= N_NODES) return;
    int v = wid;
    float dv = dinv[v];
    int beg = rowptr[v], end = rowptr[v + 1];
    float acc = H[(size_t)v * 64 + lane] * dv * dv;  // self-loop
    for (int j0 = beg; j0 < end; j0 += 64) {
        int myj = j0 + lane;
        int s = 0;
        float w = 0.f;
        if (myj < end) {
            s = colsrc[myj];
            w = dinv[s] * dv;
        }
        int cnt = min(64, end - j0);
        for (int t = 0; t < cnt; ++t) {
            int sv = __shfl(s, t);
            float wv = __shfl(w, t);
            acc += H[(size_t)sv * 64 + lane] * wv;
        }
    }
    acc += bias[lane];
    acc = acc > 0.f ? acc : NEG_SLOPE * acc;
    out[(size_t)v * 64 + lane] = acc;
}

__global__ void gather32_kernel(const float* __restrict__ H, const int* __restrict__ rowptr,
                                const int* __restrict__ colsrc, const float* __restrict__ dinv,
                                const float* __restrict__ bias, float* __restrict__ out) {
    int gw = (blockIdx.x * blockDim.x + threadIdx.x) >> 5;
    int lane = threadIdx.x & 31;
    if (gw >= N_NODES) return;
    int v = gw;
    float dv = dinv[v];
    int beg = rowptr[v], end = rowptr[v + 1];
    float acc = H[(size_t)v * 32 + lane] * dv * dv;  // self-loop
    for (int j0 = beg; j0 < end; j0 += 32) {
        int myj = j0 + lane;
        int s = 0;
        float w = 0.f;
        if (myj < end) {
            s = colsrc[myj];
            w = dinv[s] * dv;
        }
        int cnt = min(32, end - j0);
        for (int t = 0; t < cnt; ++t) {
            int sv = __shfl(s, t, 32);
            float wv = __shfl(w, t, 32);
            acc += H[(size_t)sv * 32 + lane] * wv;
        }
    }
    acc += bias[lane];
    out[(size_t)v * 32 + lane] = acc;
}

extern "C" void kernel_launch(void* const* d_in, const int* in_sizes, int n_in,
                              void* d_out, int out_size, void* d_ws, size_t ws_size,
                              hipStream_t stream) {
    const float* x = (const float*)d_in[0];
    const int* ei = (const int*)d_in[1];  // [2,E]: src row then dst row
    const float* W1 = (const float*)d_in[2];
    const float* b1 = (const float*)d_in[3];
    const float* W2 = (const float*)d_in[4];
    const float* b2 = (const float*)d_in[5];
    float* out = (float*)d_out;

    const int* src = ei;
    const int* dst = ei + N_EDGES;

    // workspace layout (~59 MB)
    float* dinv = (float*)d_ws;               // N
    int* rowptr = (int*)(dinv + N_NODES);     // N+1
    int* cnt = rowptr + N_NODES + 1;          // N
    int* pos = cnt + N_NODES;                 // N
    int* bsum = pos + N_NODES;                // NBLK
    int* bofs = bsum + NBLK;                  // NBLK
    int* colsrc = bofs + NBLK;                // E
    float* h1 = (float*)(colsrc + N_EDGES);   // N*64
    float* h1p = h1 + (size_t)N_NODES * DIN;  // N*64
    float* h2 = h1;                           // alias: h1 dead after gather64

    // CSR build + norms
    zero_cnt_kernel<<<NBLK, 256, 0, stream>>>(cnt);
    count_kernel<<<(N_EDGES + 255) / 256, 256, 0, stream>>>(dst, cnt);
    blocksum_kernel<<<NBLK, 256, 0, stream>>>(cnt, bsum);
    scan_bsum_kernel<<<1, 512, 0, stream>>>(bsum, bofs);
    rowptr_kernel<<<NBLK, 256, 0, stream>>>(cnt, bofs, rowptr, pos, dinv);
    fill_kernel<<<(N_EDGES + 255) / 256, 256, 0, stream>>>(src, dst, pos, colsrc);

    // layer 1
    gemm_k64_n64_kernel<<<N_NODES / 4, 256, 0, stream>>>(x, W1, h1);
    gather64_kernel<<<(N_NODES * 64 + 255) / 256, 256, 0, stream>>>(h1, rowptr, colsrc, dinv, b1, h1p);

    // layer 2
    gemm_k64_n32_kernel<<<N_NODES / 8, 256, 0, stream>>>(h1p, W2, h2);
    gather32_kernel<<<(N_NODES * 32 + 255) / 256, 256, 0, stream>>>(h2, rowptr, colsrc, dinv, b2, out);
}